// Round 4
// baseline (2299.692 us; speedup 1.0000x reference)
//
#include <hip/hip_runtime.h>
#include <hip/hip_bf16.h>

#define DIM 256
#define HEADS 4
#define NEG_SLOPE 0.01f

typedef unsigned short u16;
typedef __attribute__((ext_vector_type(8))) short short8;
typedef __attribute__((ext_vector_type(4))) float f32x4;
typedef __attribute__((ext_vector_type(4))) unsigned short u16x4;

// ---- bf16 split helpers ----
__device__ __forceinline__ u16 f2bf(float f) {
    unsigned u = __float_as_uint(f);
    unsigned r = (u + 0x7fffu + ((u >> 16) & 1u)) >> 16;
    return (u16)r;
}
__device__ __forceinline__ float bf2f(u16 h) {
    return __uint_as_float(((unsigned)h) << 16);
}

// ---- sortable-uint encoding for float atomicMax ----
__device__ __forceinline__ unsigned f2sort(float f) {
    unsigned u = __float_as_uint(f);
    return (u & 0x80000000u) ? ~u : (u | 0x80000000u);
}
__device__ __forceinline__ float sort2f(unsigned s) {
    return (s & 0x80000000u) ? __uint_as_float(s & 0x7fffffffu)
                             : __uint_as_float(~s);
}

// K0: split-transpose w_q (k-major fp32) -> BThi/BTlo (n-major bf16)
__global__ __launch_bounds__(256) void prepb_kernel(const float* __restrict__ B,
                                                    u16* __restrict__ BThi,
                                                    u16* __restrict__ BTlo) {
    int k = blockIdx.x;
    int n = threadIdx.x;
    float f = B[k * 256 + n];
    u16 hi = f2bf(f);
    u16 lo = f2bf(f - bf2f(hi));
    BThi[n * 256 + k] = hi;
    BTlo[n * 256 + k] = lo;
}

// K1: beta[j,h] = sum_{d<64} x_edge[j, h*64+d] * weight[h, d]
__global__ __launch_bounds__(256) void beta_kernel(const float* __restrict__ xe,
                                                   const float* __restrict__ weight,
                                                   float* __restrict__ beta, int NE) {
    int wid = blockIdx.x * 4 + (threadIdx.x >> 6);
    if (wid >= NE) return;
    int lane = threadIdx.x & 63;
    int h = lane >> 4;
    float4 v = *reinterpret_cast<const float4*>(xe + (size_t)wid * DIM + lane * 4);
    float4 w = *reinterpret_cast<const float4*>(weight + h * 128 + (lane & 15) * 4);
    float p = v.x * w.x + v.y * w.y + v.z * w.z + v.w * w.w;
    p += __shfl_xor(p, 1);
    p += __shfl_xor(p, 2);
    p += __shfl_xor(p, 4);
    p += __shfl_xor(p, 8);
    if ((lane & 15) == 0) beta[(size_t)wid * 4 + h] = p;
}

// K2: xq = x_q @ w_q via split-bf16 MFMA (3-product), fused gamma epilogue.
// 512 threads = 8 waves (2 row-halves x 4 col-heads). BM=256, BN=256, BK=32.
// LDS tiles [256][32] u16, XOR-swizzled: phys 16B-chunk = chunk ^ (row&3).
__global__ __launch_bounds__(512, 4) void gemm_gamma_kernel(const float* __restrict__ A,
                                                            const u16* __restrict__ BThi,
                                                            const u16* __restrict__ BTlo,
                                                            const float* __restrict__ weight,
                                                            u16* __restrict__ xq_out,
                                                            float* __restrict__ gamma, int NQ) {
    __shared__ u16 Ahi_s[256 * 32];
    __shared__ u16 Alo_s[256 * 32];
    __shared__ u16 Bhi_s[256 * 32];
    __shared__ u16 Blo_s[256 * 32];

    const int t = threadIdx.x;
    const int lane = t & 63;
    const int wid = t >> 6;
    const int wr = wid >> 2;       // row half 0/1
    const int wc = wid & 3;        // head / 64-col group
    const int lr = lane & 15;
    const int kg = lane >> 4;
    const long brow = (long)blockIdx.x * 256;

    f32x4 acc[8][4];
#pragma unroll
    for (int m = 0; m < 8; ++m)
#pragma unroll
        for (int n = 0; n < 4; ++n) acc[m][n] = (f32x4){0.f, 0.f, 0.f, 0.f};

    // staging indices (constant across k-steps)
    // A: slot = t + i*512 -> row = slot>>3, c4 = slot&7 (8B units)
    // B: slot = t + i*512 -> n = slot>>2, c = slot&3 (16B chunks)
    for (int k0 = 0; k0 < DIM; k0 += 32) {
#pragma unroll
        for (int i = 0; i < 4; ++i) {
            int slot = t + i * 512;
            int row = slot >> 3, c4 = slot & 7;
            long grow = brow + row;
            if (grow >= NQ) grow = NQ - 1;
            float4 v = *reinterpret_cast<const float4*>(A + grow * DIM + k0 + c4 * 4);
            u16x4 hi, lo;
            hi.x = f2bf(v.x); lo.x = f2bf(v.x - bf2f(hi.x));
            hi.y = f2bf(v.y); lo.y = f2bf(v.y - bf2f(hi.y));
            hi.z = f2bf(v.z); lo.z = f2bf(v.z - bf2f(hi.z));
            hi.w = f2bf(v.w); lo.w = f2bf(v.w - bf2f(hi.w));
            int off = row * 32 + (((c4 >> 1) ^ (row & 3)) << 3) + ((c4 & 1) << 2);
            *reinterpret_cast<u16x4*>(&Ahi_s[off]) = hi;
            *reinterpret_cast<u16x4*>(&Alo_s[off]) = lo;
        }
#pragma unroll
        for (int i = 0; i < 2; ++i) {
            int slot = t + i * 512;
            int n = slot >> 2, c = slot & 3;
            uint4 vh = *reinterpret_cast<const uint4*>(BThi + n * 256 + k0 + c * 8);
            uint4 vl = *reinterpret_cast<const uint4*>(BTlo + n * 256 + k0 + c * 8);
            int off = n * 32 + ((c ^ (n & 3)) << 3);
            *reinterpret_cast<uint4*>(&Bhi_s[off]) = vh;
            *reinterpret_cast<uint4*>(&Blo_s[off]) = vl;
        }
        __syncthreads();

        short8 bh[4], bl[4];
#pragma unroll
        for (int n = 0; n < 4; ++n) {
            int nn = wc * 64 + n * 16 + lr;
            int off = nn * 32 + ((kg ^ (nn & 3)) << 3);
            bh[n] = *reinterpret_cast<const short8*>(&Bhi_s[off]);
            bl[n] = *reinterpret_cast<const short8*>(&Blo_s[off]);
        }
#pragma unroll
        for (int m = 0; m < 8; ++m) {
            int rr = wr * 128 + m * 16 + lr;
            int off = rr * 32 + ((kg ^ (rr & 3)) << 3);
            short8 ah = *reinterpret_cast<const short8*>(&Ahi_s[off]);
            short8 al = *reinterpret_cast<const short8*>(&Alo_s[off]);
#pragma unroll
            for (int n = 0; n < 4; ++n) {
                acc[m][n] = __builtin_amdgcn_mfma_f32_16x16x32_bf16(ah, bh[n], acc[m][n], 0, 0, 0);
                acc[m][n] = __builtin_amdgcn_mfma_f32_16x16x32_bf16(ah, bl[n], acc[m][n], 0, 0, 0);
                acc[m][n] = __builtin_amdgcn_mfma_f32_16x16x32_bf16(al, bh[n], acc[m][n], 0, 0, 0);
            }
        }
        __syncthreads();
    }

    // epilogue: bf16 xq stores + fused per-head gamma
    float wv[4];
#pragma unroll
    for (int n = 0; n < 4; ++n) wv[n] = weight[wc * 128 + 64 + n * 16 + lr];

#pragma unroll
    for (int m = 0; m < 8; ++m) {
        long rowm = brow + wr * 128 + m * 16 + kg * 4;
#pragma unroll
        for (int r = 0; r < 4; ++r) {
            long row = rowm + r;
            bool ok = row < NQ;
            float p = 0.f;
#pragma unroll
            for (int n = 0; n < 4; ++n) {
                float v = acc[m][n][r];
                if (ok) xq_out[row * DIM + wc * 64 + n * 16 + lr] = f2bf(v);
                p = fmaf(v, wv[n], p);
            }
            p += __shfl_xor(p, 1);
            p += __shfl_xor(p, 2);
            p += __shfl_xor(p, 4);
            p += __shfl_xor(p, 8);
            if (ok && lr == 0) gamma[row * 4 + wc] = p;
        }
    }
}

// K3: logit = leaky_relu(beta[eid] + gamma); atomicMax segmax; histogram counts
__global__ __launch_bounds__(256) void logits_kernel(const float* __restrict__ beta,
                                                     const float* __restrict__ gamma,
                                                     const int* __restrict__ eids,
                                                     float* __restrict__ logit,
                                                     unsigned* __restrict__ segmax,
                                                     unsigned* __restrict__ counts, int NQ) {
    int e = blockIdx.x * blockDim.x + threadIdx.x;
    if (e >= NQ) return;
    int j = eids[e];
    float4 g = *reinterpret_cast<const float4*>(gamma + (size_t)e * 4);
    float4 b = *reinterpret_cast<const float4*>(beta + (size_t)j * 4);
    float l[4] = {b.x + g.x, b.y + g.y, b.z + g.z, b.w + g.w};
#pragma unroll
    for (int h = 0; h < 4; ++h) {
        l[h] = l[h] > 0.f ? l[h] : NEG_SLOPE * l[h];
        atomicMax(&segmax[(size_t)j * 4 + h], f2sort(l[h]));
    }
    atomicAdd(&counts[j], 1u);
    *reinterpret_cast<float4*>(logit + (size_t)e * 4) = make_float4(l[0], l[1], l[2], l[3]);
}

// K4: ex = exp(logit - segmax[eid]); atomicAdd segsum (in place over logit)
__global__ __launch_bounds__(256) void exp_kernel(float* __restrict__ logit,
                                                  const int* __restrict__ eids,
                                                  const unsigned* __restrict__ segmax,
                                                  float* __restrict__ segsum, int NQ) {
    int e = blockIdx.x * blockDim.x + threadIdx.x;
    if (e >= NQ) return;
    int j = eids[e];
    float4 l = *reinterpret_cast<const float4*>(logit + (size_t)e * 4);
    uint4 m = *reinterpret_cast<const uint4*>(segmax + (size_t)j * 4);
    float ex[4] = {__expf(l.x - sort2f(m.x)), __expf(l.y - sort2f(m.y)),
                   __expf(l.z - sort2f(m.z)), __expf(l.w - sort2f(m.w))};
    *reinterpret_cast<float4*>(logit + (size_t)e * 4) = make_float4(ex[0], ex[1], ex[2], ex[3]);
#pragma unroll
    for (int h = 0; h < 4; ++h) atomicAdd(&segsum[(size_t)j * 4 + h], ex[h]);
}

// ---- CSR build ----
__global__ __launch_bounds__(256) void scan1_kernel(const unsigned* __restrict__ counts,
                                                    unsigned* __restrict__ offs,
                                                    unsigned* __restrict__ blocksums, int NE) {
    __shared__ unsigned s[256];
    int t = threadIdx.x;
    int base = blockIdx.x * 1024 + t * 4;
    unsigned v[4], sum = 0;
#pragma unroll
    for (int i = 0; i < 4; ++i) {
        v[i] = (base + i < NE) ? counts[base + i] : 0u;
        sum += v[i];
    }
    s[t] = sum;
    __syncthreads();
    for (int off = 1; off < 256; off <<= 1) {
        unsigned y = (t >= off) ? s[t - off] : 0u;
        __syncthreads();
        s[t] += y;
        __syncthreads();
    }
    unsigned excl = s[t] - sum;
#pragma unroll
    for (int i = 0; i < 4; ++i) {
        if (base + i < NE) offs[base + i] = excl;
        excl += v[i];
    }
    if (t == 255) blocksums[blockIdx.x] = s[255];
}

__global__ __launch_bounds__(256) void scan2_kernel(unsigned* __restrict__ blocksums, int NB) {
    __shared__ unsigned s[256];
    int t = threadIdx.x;
    unsigned v = (t < NB) ? blocksums[t] : 0u;
    s[t] = v;
    __syncthreads();
    for (int off = 1; off < 256; off <<= 1) {
        unsigned y = (t >= off) ? s[t - off] : 0u;
        __syncthreads();
        s[t] += y;
        __syncthreads();
    }
    if (t < NB) blocksums[t] = s[t] - v;
}

__global__ __launch_bounds__(256) void scan3_kernel(unsigned* __restrict__ offs,
                                                    const unsigned* __restrict__ blocksums,
                                                    unsigned* __restrict__ cursor, int NE) {
    int t = threadIdx.x;
    int base = blockIdx.x * 1024 + t * 4;
    unsigned add = blocksums[blockIdx.x];
#pragma unroll
    for (int i = 0; i < 4; ++i) {
        if (base + i < NE) {
            unsigned o = offs[base + i] + add;
            offs[base + i] = o;
            cursor[base + i] = o;
        }
    }
}

__global__ __launch_bounds__(256) void fill_kernel(const int* __restrict__ eids,
                                                   unsigned* __restrict__ cursor,
                                                   int* __restrict__ qlist, int NQ) {
    int e = blockIdx.x * blockDim.x + threadIdx.x;
    if (e >= NQ) return;
    int j = eids[e];
    unsigned pos = atomicAdd(&cursor[j], 1u);
    qlist[pos] = e;
}

// gather: out[j,:] = sum_{q in seg(j)} (ex[q,h]/(segsum[j,h]+eps)) * xq_bf16[q,:]
__global__ __launch_bounds__(256) void gather_kernel(const float* __restrict__ ex,
                                                     const float* __restrict__ segsum,
                                                     const unsigned* __restrict__ offs,
                                                     const unsigned* __restrict__ counts,
                                                     const int* __restrict__ qlist,
                                                     const u16* __restrict__ xq,
                                                     float* __restrict__ out, int NE) {
    int j = blockIdx.x * 4 + (threadIdx.x >> 6);
    if (j >= NE) return;
    int lane = threadIdx.x & 63;
    int h = lane >> 4;
    unsigned beg = offs[j];
    unsigned n = counts[j];
    float inv = 1.0f / (segsum[(size_t)j * 4 + h] + 1e-16f);
    float4 acc = make_float4(0.f, 0.f, 0.f, 0.f);
    for (unsigned i = 0; i < n; ++i) {
        int q = qlist[beg + i];
        float w = ex[(size_t)q * 4 + h] * inv;
        u16x4 v = *reinterpret_cast<const u16x4*>(xq + (size_t)q * DIM + lane * 4);
        acc.x = fmaf(w, bf2f(v.x), acc.x);
        acc.y = fmaf(w, bf2f(v.y), acc.y);
        acc.z = fmaf(w, bf2f(v.z), acc.z);
        acc.w = fmaf(w, bf2f(v.w), acc.w);
    }
    *reinterpret_cast<float4*>(out + (size_t)j * DIM + lane * 4) = acc;
}

extern "C" void kernel_launch(void* const* d_in, const int* in_sizes, int n_in,
                              void* d_out, int out_size, void* d_ws, size_t ws_size,
                              hipStream_t stream) {
    (void)n_in; (void)out_size; (void)ws_size;
    const float* x_q    = (const float*)d_in[0];
    const float* x_edge = (const float*)d_in[1];
    const float* w_q    = (const float*)d_in[2];
    const float* weight = (const float*)d_in[3];
    const int*   eids   = (const int*)d_in[4];
    const int NQ = in_sizes[0] / DIM;   // 500000
    const int NE = in_sizes[1] / DIM;   // 250000
    float* out = (float*)d_out;

    // workspace layout
    u16*      xq        = (u16*)d_ws;                           // NQ*256 bf16
    float*    gamma     = (float*)(xq + (size_t)NQ * DIM);      // NQ*4
    float*    logit     = gamma + (size_t)NQ * 4;               // NQ*4 (becomes ex)
    float*    beta      = logit + (size_t)NQ * 4;               // NE*4
    unsigned* segmax    = (unsigned*)(beta + (size_t)NE * 4);   // NE*4
    float*    segsum    = (float*)(segmax + (size_t)NE * 4);    // NE*4
    unsigned* counts    = (unsigned*)(segsum + (size_t)NE * 4); // NE
    unsigned* offs      = counts + NE;                          // NE
    unsigned* cursor    = offs + NE;                            // NE
    int*      qlist     = (int*)(cursor + NE);                  // NQ
    unsigned* blocksums = (unsigned*)(qlist + NQ);              // 256
    u16*      BThi      = (u16*)(blocksums + 256);              // 256*256
    u16*      BTlo      = BThi + 256 * 256;                     // 256*256

    const int NB = (NE + 1023) / 1024;

    hipMemsetAsync(segmax, 0, (size_t)NE * 4 * sizeof(unsigned), stream);
    hipMemsetAsync(segsum, 0, (size_t)NE * 4 * sizeof(float), stream);
    hipMemsetAsync(counts, 0, (size_t)NE * sizeof(unsigned), stream);

    prepb_kernel<<<256, 256, 0, stream>>>(w_q, BThi, BTlo);
    beta_kernel<<<(NE + 3) / 4, 256, 0, stream>>>(x_edge, weight, beta, NE);
    gemm_gamma_kernel<<<(NQ + 255) / 256, 512, 0, stream>>>(x_q, BThi, BTlo, weight, xq, gamma, NQ);
    logits_kernel<<<(NQ + 255) / 256, 256, 0, stream>>>(beta, gamma, eids, logit, segmax, counts, NQ);
    exp_kernel<<<(NQ + 255) / 256, 256, 0, stream>>>(logit, eids, segmax, segsum, NQ);
    scan1_kernel<<<NB, 256, 0, stream>>>(counts, offs, blocksums, NE);
    scan2_kernel<<<1, 256, 0, stream>>>(blocksums, NB);
    scan3_kernel<<<NB, 256, 0, stream>>>(offs, blocksums, cursor, NE);
    fill_kernel<<<(NQ + 255) / 256, 256, 0, stream>>>(eids, cursor, qlist, NQ);
    gather_kernel<<<(NE + 3) / 4, 256, 0, stream>>>(logit, segsum, offs, counts, qlist, xq, out, NE);
}

// Round 5
// 821.684 us; speedup vs baseline: 2.7988x; 2.7988x over previous
//
#include <hip/hip_runtime.h>
#include <hip/hip_bf16.h>

#define DIM 256
#define HEADS 4
#define NEG_SLOPE 0.01f

typedef unsigned short u16;
typedef __attribute__((ext_vector_type(8))) short short8;
typedef __attribute__((ext_vector_type(4))) float f32x4;
typedef __attribute__((ext_vector_type(4))) unsigned short u16x4;

// ---- bf16 helpers ----
__device__ __forceinline__ u16 f2bf(float f) {           // RTN-even
    unsigned u = __float_as_uint(f);
    unsigned r = (u + 0x7fffu + ((u >> 16) & 1u)) >> 16;
    return (u16)r;
}
__device__ __forceinline__ float bf2f(u16 h) {
    return __uint_as_float(((unsigned)h) << 16);
}
// truncation-based split of two floats -> packed hi pair / lo pair (bf16x2)
__device__ __forceinline__ void split2(float f0, float f1, unsigned& hi, unsigned& lo) {
    unsigned u0 = __float_as_uint(f0), u1 = __float_as_uint(f1);
    hi = (u0 >> 16) | (u1 & 0xffff0000u);
    float r0 = f0 - __uint_as_float(u0 & 0xffff0000u);
    float r1 = f1 - __uint_as_float(u1 & 0xffff0000u);
    lo = (__float_as_uint(r0) >> 16) | (__float_as_uint(r1) & 0xffff0000u);
}

// ---- sortable-uint encoding for float atomicMax ----
__device__ __forceinline__ unsigned f2sort(float f) {
    unsigned u = __float_as_uint(f);
    return (u & 0x80000000u) ? ~u : (u | 0x80000000u);
}
__device__ __forceinline__ float sort2f(unsigned s) {
    return (s & 0x80000000u) ? __uint_as_float(s & 0x7fffffffu)
                             : __uint_as_float(~s);
}

// K0: split-transpose w_q (k-major fp32) -> BThi/BTlo (n-major bf16, RTN)
__global__ __launch_bounds__(256) void prepb_kernel(const float* __restrict__ B,
                                                    u16* __restrict__ BThi,
                                                    u16* __restrict__ BTlo) {
    int k = blockIdx.x;
    int n = threadIdx.x;
    float f = B[k * 256 + n];
    u16 hi = f2bf(f);
    u16 lo = f2bf(f - bf2f(hi));
    BThi[n * 256 + k] = hi;
    BTlo[n * 256 + k] = lo;
}

// K1: beta[j,h] = sum_{d<64} x_edge[j, h*64+d] * weight[h, d]
__global__ __launch_bounds__(256) void beta_kernel(const float* __restrict__ xe,
                                                   const float* __restrict__ weight,
                                                   float* __restrict__ beta, int NE) {
    int wid = blockIdx.x * 4 + (threadIdx.x >> 6);
    if (wid >= NE) return;
    int lane = threadIdx.x & 63;
    int h = lane >> 4;
    float4 v = *reinterpret_cast<const float4*>(xe + (size_t)wid * DIM + lane * 4);
    float4 w = *reinterpret_cast<const float4*>(weight + h * 128 + (lane & 15) * 4);
    float p = v.x * w.x + v.y * w.y + v.z * w.z + v.w * w.w;
    p += __shfl_xor(p, 1);
    p += __shfl_xor(p, 2);
    p += __shfl_xor(p, 4);
    p += __shfl_xor(p, 8);
    if ((lane & 15) == 0) beta[(size_t)wid * 4 + h] = p;
}

// K2: xq = x_q @ w_q via split-bf16 MFMA (3-product), fused gamma epilogue.
// 512 threads = 8 waves (2 row-halves x 4 col-heads). BM=256, BN=256, BK=32.
// LDS tiles [256][32] u16; 16B-chunk swizzle: phys = c ^ (row&3) ^ ((row>>2)&3).
__global__ __launch_bounds__(512, 2) void gemm_gamma_kernel(const float* __restrict__ A,
                                                            const u16* __restrict__ BThi,
                                                            const u16* __restrict__ BTlo,
                                                            const float* __restrict__ weight,
                                                            u16* __restrict__ xq_out,
                                                            float* __restrict__ gamma, int NQ) {
    __shared__ u16 Ahi_s[256 * 32];
    __shared__ u16 Alo_s[256 * 32];
    __shared__ u16 Bhi_s[256 * 32];
    __shared__ u16 Blo_s[256 * 32];

    const int t = threadIdx.x;
    const int lane = t & 63;
    const int wid = t >> 6;
    const int wr = wid >> 2;       // row half 0/1
    const int wc = wid & 3;        // head / 64-col group
    const int lr = lane & 15;
    const int kg = lane >> 4;
    const long brow = (long)blockIdx.x * 256;

    f32x4 acc[8][4];
#pragma unroll
    for (int m = 0; m < 8; ++m)
#pragma unroll
        for (int n = 0; n < 4; ++n) acc[m][n] = (f32x4){0.f, 0.f, 0.f, 0.f};

    for (int k0 = 0; k0 < DIM; k0 += 32) {
        // stage A tile (256 rows x 32 k) fp32 -> bf16 hi/lo (truncation split)
#pragma unroll
        for (int i = 0; i < 4; ++i) {
            int slot = t + i * 512;
            int row = slot >> 3, c4 = slot & 7;   // c4: 8B unit (4 u16)
            long grow = brow + row;
            if (grow >= NQ) grow = NQ - 1;
            float4 v = *reinterpret_cast<const float4*>(A + grow * DIM + k0 + c4 * 4);
            unsigned h01, l01, h23, l23;
            split2(v.x, v.y, h01, l01);
            split2(v.z, v.w, h23, l23);
            int swz = (c4 >> 1) ^ (row & 3) ^ ((row >> 2) & 3);
            int off = row * 32 + (swz << 3) + ((c4 & 1) << 2);
            *reinterpret_cast<uint2*>(&Ahi_s[off]) = make_uint2(h01, h23);
            *reinterpret_cast<uint2*>(&Alo_s[off]) = make_uint2(l01, l23);
        }
        // stage B tile (256 n x 32 k) bf16 copy from pre-transposed hi/lo
#pragma unroll
        for (int i = 0; i < 2; ++i) {
            int slot = t + i * 512;
            int n = slot >> 2, c = slot & 3;      // c: 16B chunk
            uint4 vh = *reinterpret_cast<const uint4*>(BThi + n * 256 + k0 + c * 8);
            uint4 vl = *reinterpret_cast<const uint4*>(BTlo + n * 256 + k0 + c * 8);
            int swz = c ^ (n & 3) ^ ((n >> 2) & 3);
            int off = n * 32 + (swz << 3);
            *reinterpret_cast<uint4*>(&Bhi_s[off]) = vh;
            *reinterpret_cast<uint4*>(&Blo_s[off]) = vl;
        }
        __syncthreads();

        short8 bh[4], bl[4];
#pragma unroll
        for (int n = 0; n < 4; ++n) {
            int nn = wc * 64 + n * 16 + lr;
            int off = nn * 32 + ((kg ^ (nn & 3) ^ ((nn >> 2) & 3)) << 3);
            bh[n] = *reinterpret_cast<const short8*>(&Bhi_s[off]);
            bl[n] = *reinterpret_cast<const short8*>(&Blo_s[off]);
        }
#pragma unroll
        for (int m = 0; m < 8; ++m) {
            int rr = wr * 128 + m * 16 + lr;
            int off = rr * 32 + ((kg ^ (rr & 3) ^ ((rr >> 2) & 3)) << 3);
            short8 ah = *reinterpret_cast<const short8*>(&Ahi_s[off]);
            short8 al = *reinterpret_cast<const short8*>(&Alo_s[off]);
#pragma unroll
            for (int n = 0; n < 4; ++n) {
                acc[m][n] = __builtin_amdgcn_mfma_f32_16x16x32_bf16(ah, bh[n], acc[m][n], 0, 0, 0);
                acc[m][n] = __builtin_amdgcn_mfma_f32_16x16x32_bf16(ah, bl[n], acc[m][n], 0, 0, 0);
                acc[m][n] = __builtin_amdgcn_mfma_f32_16x16x32_bf16(al, bh[n], acc[m][n], 0, 0, 0);
            }
        }
        __syncthreads();
    }

    // epilogue: bf16 xq stores + fused per-head gamma
    float wv[4];
#pragma unroll
    for (int n = 0; n < 4; ++n) wv[n] = weight[wc * 128 + 64 + n * 16 + lr];

#pragma unroll
    for (int m = 0; m < 8; ++m) {
        long rowm = brow + wr * 128 + m * 16 + kg * 4;
#pragma unroll
        for (int r = 0; r < 4; ++r) {
            long row = rowm + r;
            bool ok = row < NQ;
            float p = 0.f;
#pragma unroll
            for (int n = 0; n < 4; ++n) {
                float v = acc[m][n][r];
                if (ok) xq_out[row * DIM + wc * 64 + n * 16 + lr] = f2bf(v);
                p = fmaf(v, wv[n], p);
            }
            p += __shfl_xor(p, 1);
            p += __shfl_xor(p, 2);
            p += __shfl_xor(p, 4);
            p += __shfl_xor(p, 8);
            if (ok && lr == 0) gamma[row * 4 + wc] = p;
        }
    }
}

// K3: logit = leaky_relu(beta[eid] + gamma); atomicMax segmax; histogram counts
__global__ __launch_bounds__(256) void logits_kernel(const float* __restrict__ beta,
                                                     const float* __restrict__ gamma,
                                                     const int* __restrict__ eids,
                                                     float* __restrict__ logit,
                                                     unsigned* __restrict__ segmax,
                                                     unsigned* __restrict__ counts, int NQ) {
    int e = blockIdx.x * blockDim.x + threadIdx.x;
    if (e >= NQ) return;
    int j = eids[e];
    float4 g = *reinterpret_cast<const float4*>(gamma + (size_t)e * 4);
    float4 b = *reinterpret_cast<const float4*>(beta + (size_t)j * 4);
    float l[4] = {b.x + g.x, b.y + g.y, b.z + g.z, b.w + g.w};
#pragma unroll
    for (int h = 0; h < 4; ++h) {
        l[h] = l[h] > 0.f ? l[h] : NEG_SLOPE * l[h];
        atomicMax(&segmax[(size_t)j * 4 + h], f2sort(l[h]));
    }
    atomicAdd(&counts[j], 1u);
    *reinterpret_cast<float4*>(logit + (size_t)e * 4) = make_float4(l[0], l[1], l[2], l[3]);
}

// K4: ex = exp(logit - segmax[eid]); atomicAdd segsum (in place over logit)
__global__ __launch_bounds__(256) void exp_kernel(float* __restrict__ logit,
                                                  const int* __restrict__ eids,
                                                  const unsigned* __restrict__ segmax,
                                                  float* __restrict__ segsum, int NQ) {
    int e = blockIdx.x * blockDim.x + threadIdx.x;
    if (e >= NQ) return;
    int j = eids[e];
    float4 l = *reinterpret_cast<const float4*>(logit + (size_t)e * 4);
    uint4 m = *reinterpret_cast<const uint4*>(segmax + (size_t)j * 4);
    float ex[4] = {__expf(l.x - sort2f(m.x)), __expf(l.y - sort2f(m.y)),
                   __expf(l.z - sort2f(m.z)), __expf(l.w - sort2f(m.w))};
    *reinterpret_cast<float4*>(logit + (size_t)e * 4) = make_float4(ex[0], ex[1], ex[2], ex[3]);
#pragma unroll
    for (int h = 0; h < 4; ++h) atomicAdd(&segsum[(size_t)j * 4 + h], ex[h]);
}

// ---- CSR build ----
__global__ __launch_bounds__(256) void scan1_kernel(const unsigned* __restrict__ counts,
                                                    unsigned* __restrict__ offs,
                                                    unsigned* __restrict__ blocksums, int NE) {
    __shared__ unsigned s[256];
    int t = threadIdx.x;
    int base = blockIdx.x * 1024 + t * 4;
    unsigned v[4], sum = 0;
#pragma unroll
    for (int i = 0; i < 4; ++i) {
        v[i] = (base + i < NE) ? counts[base + i] : 0u;
        sum += v[i];
    }
    s[t] = sum;
    __syncthreads();
    for (int off = 1; off < 256; off <<= 1) {
        unsigned y = (t >= off) ? s[t - off] : 0u;
        __syncthreads();
        s[t] += y;
        __syncthreads();
    }
    unsigned excl = s[t] - sum;
#pragma unroll
    for (int i = 0; i < 4; ++i) {
        if (base + i < NE) offs[base + i] = excl;
        excl += v[i];
    }
    if (t == 255) blocksums[blockIdx.x] = s[255];
}

__global__ __launch_bounds__(256) void scan2_kernel(unsigned* __restrict__ blocksums, int NB) {
    __shared__ unsigned s[256];
    int t = threadIdx.x;
    unsigned v = (t < NB) ? blocksums[t] : 0u;
    s[t] = v;
    __syncthreads();
    for (int off = 1; off < 256; off <<= 1) {
        unsigned y = (t >= off) ? s[t - off] : 0u;
        __syncthreads();
        s[t] += y;
        __syncthreads();
    }
    if (t < NB) blocksums[t] = s[t] - v;
}

__global__ __launch_bounds__(256) void scan3_kernel(unsigned* __restrict__ offs,
                                                    const unsigned* __restrict__ blocksums,
                                                    unsigned* __restrict__ cursor, int NE) {
    int t = threadIdx.x;
    int base = blockIdx.x * 1024 + t * 4;
    unsigned add = blocksums[blockIdx.x];
#pragma unroll
    for (int i = 0; i < 4; ++i) {
        if (base + i < NE) {
            unsigned o = offs[base + i] + add;
            offs[base + i] = o;
            cursor[base + i] = o;
        }
    }
}

__global__ __launch_bounds__(256) void fill_kernel(const int* __restrict__ eids,
                                                   unsigned* __restrict__ cursor,
                                                   int* __restrict__ qlist, int NQ) {
    int e = blockIdx.x * blockDim.x + threadIdx.x;
    if (e >= NQ) return;
    int j = eids[e];
    unsigned pos = atomicAdd(&cursor[j], 1u);
    qlist[pos] = e;
}

// gather: out[j,:] = sum_{q in seg(j)} (ex[q,h]/(segsum[j,h]+eps)) * xq_bf16[q,:]
__global__ __launch_bounds__(256) void gather_kernel(const float* __restrict__ ex,
                                                     const float* __restrict__ segsum,
                                                     const unsigned* __restrict__ offs,
                                                     const unsigned* __restrict__ counts,
                                                     const int* __restrict__ qlist,
                                                     const u16* __restrict__ xq,
                                                     float* __restrict__ out, int NE) {
    int j = blockIdx.x * 4 + (threadIdx.x >> 6);
    if (j >= NE) return;
    int lane = threadIdx.x & 63;
    int h = lane >> 4;
    unsigned beg = offs[j];
    unsigned n = counts[j];
    float inv = 1.0f / (segsum[(size_t)j * 4 + h] + 1e-16f);
    float4 acc = make_float4(0.f, 0.f, 0.f, 0.f);
    for (unsigned i = 0; i < n; ++i) {
        int q = qlist[beg + i];
        float w = ex[(size_t)q * 4 + h] * inv;
        u16x4 v = *reinterpret_cast<const u16x4*>(xq + (size_t)q * DIM + lane * 4);
        acc.x = fmaf(w, bf2f(v.x), acc.x);
        acc.y = fmaf(w, bf2f(v.y), acc.y);
        acc.z = fmaf(w, bf2f(v.z), acc.z);
        acc.w = fmaf(w, bf2f(v.w), acc.w);
    }
    *reinterpret_cast<float4*>(out + (size_t)j * DIM + lane * 4) = acc;
}

extern "C" void kernel_launch(void* const* d_in, const int* in_sizes, int n_in,
                              void* d_out, int out_size, void* d_ws, size_t ws_size,
                              hipStream_t stream) {
    (void)n_in; (void)out_size; (void)ws_size;
    const float* x_q    = (const float*)d_in[0];
    const float* x_edge = (const float*)d_in[1];
    const float* w_q    = (const float*)d_in[2];
    const float* weight = (const float*)d_in[3];
    const int*   eids   = (const int*)d_in[4];
    const int NQ = in_sizes[0] / DIM;   // 500000
    const int NE = in_sizes[1] / DIM;   // 250000
    float* out = (float*)d_out;

    // workspace layout
    u16*      xq        = (u16*)d_ws;                           // NQ*256 bf16
    float*    gamma     = (float*)(xq + (size_t)NQ * DIM);      // NQ*4
    float*    logit     = gamma + (size_t)NQ * 4;               // NQ*4 (becomes ex)
    float*    beta      = logit + (size_t)NQ * 4;               // NE*4
    unsigned* segmax    = (unsigned*)(beta + (size_t)NE * 4);   // NE*4
    float*    segsum    = (float*)(segmax + (size_t)NE * 4);    // NE*4
    unsigned* counts    = (unsigned*)(segsum + (size_t)NE * 4); // NE
    unsigned* offs      = counts + NE;                          // NE
    unsigned* cursor    = offs + NE;                            // NE
    int*      qlist     = (int*)(cursor + NE);                  // NQ
    unsigned* blocksums = (unsigned*)(qlist + NQ);              // 256
    u16*      BThi      = (u16*)(blocksums + 256);              // 256*256
    u16*      BTlo      = BThi + 256 * 256;                     // 256*256

    const int NB = (NE + 1023) / 1024;

    hipMemsetAsync(segmax, 0, (size_t)NE * 4 * sizeof(unsigned), stream);
    hipMemsetAsync(segsum, 0, (size_t)NE * 4 * sizeof(float), stream);
    hipMemsetAsync(counts, 0, (size_t)NE * sizeof(unsigned), stream);

    prepb_kernel<<<256, 256, 0, stream>>>(w_q, BThi, BTlo);
    beta_kernel<<<(NE + 3) / 4, 256, 0, stream>>>(x_edge, weight, beta, NE);
    gemm_gamma_kernel<<<(NQ + 255) / 256, 512, 0, stream>>>(x_q, BThi, BTlo, weight, xq, gamma, NQ);
    logits_kernel<<<(NQ + 255) / 256, 256, 0, stream>>>(beta, gamma, eids, logit, segmax, counts, NQ);
    exp_kernel<<<(NQ + 255) / 256, 256, 0, stream>>>(logit, eids, segmax, segsum, NQ);
    scan1_kernel<<<NB, 256, 0, stream>>>(counts, offs, blocksums, NE);
    scan2_kernel<<<1, 256, 0, stream>>>(blocksums, NB);
    scan3_kernel<<<NB, 256, 0, stream>>>(offs, blocksums, cursor, NE);
    fill_kernel<<<(NQ + 255) / 256, 256, 0, stream>>>(eids, cursor, qlist, NQ);
    gather_kernel<<<(NE + 3) / 4, 256, 0, stream>>>(logit, segsum, offs, counts, qlist, xq, out, NE);
}

// Round 6
// 581.729 us; speedup vs baseline: 3.9532x; 1.4125x over previous
//
#include <hip/hip_runtime.h>
#include <hip/hip_bf16.h>

#define DIM 256
#define HEADS 4
#define NEG_SLOPE 0.01f

typedef unsigned short u16;
typedef __attribute__((ext_vector_type(8))) short short8;
typedef __attribute__((ext_vector_type(4))) float f32x4;
typedef __attribute__((ext_vector_type(4))) unsigned short u16x4;

// ---- bf16 helpers ----
__device__ __forceinline__ u16 f2bf(float f) {           // RTN-even
    unsigned u = __float_as_uint(f);
    unsigned r = (u + 0x7fffu + ((u >> 16) & 1u)) >> 16;
    return (u16)r;
}
__device__ __forceinline__ float bf2f(u16 h) {
    return __uint_as_float(((unsigned)h) << 16);
}
// truncation-based split of two floats -> packed hi pair / lo pair (bf16x2)
__device__ __forceinline__ void split2(float f0, float f1, unsigned& hi, unsigned& lo) {
    unsigned u0 = __float_as_uint(f0), u1 = __float_as_uint(f1);
    hi = (u0 >> 16) | (u1 & 0xffff0000u);
    float r0 = f0 - __uint_as_float(u0 & 0xffff0000u);
    float r1 = f1 - __uint_as_float(u1 & 0xffff0000u);
    lo = (__float_as_uint(r0) >> 16) | (__float_as_uint(r1) & 0xffff0000u);
}

// K0: transpose w_q (k-major fp32) -> BThi (n-major bf16, RTN)
__global__ __launch_bounds__(256) void prepb_kernel(const float* __restrict__ B,
                                                    u16* __restrict__ BThi) {
    int k = blockIdx.x;
    int n = threadIdx.x;
    BThi[n * 256 + k] = f2bf(B[k * 256 + n]);
}

// K1: beta[j,h] = sum_{d<64} x_edge[j, h*64+d] * weight[h, d]
__global__ __launch_bounds__(256) void beta_kernel(const float* __restrict__ xe,
                                                   const float* __restrict__ weight,
                                                   float* __restrict__ beta, int NE) {
    int wid = blockIdx.x * 4 + (threadIdx.x >> 6);
    if (wid >= NE) return;
    int lane = threadIdx.x & 63;
    int h = lane >> 4;
    float4 v = *reinterpret_cast<const float4*>(xe + (size_t)wid * DIM + lane * 4);
    float4 w = *reinterpret_cast<const float4*>(weight + h * 128 + (lane & 15) * 4);
    float p = v.x * w.x + v.y * w.y + v.z * w.z + v.w * w.w;
    p += __shfl_xor(p, 1);
    p += __shfl_xor(p, 2);
    p += __shfl_xor(p, 4);
    p += __shfl_xor(p, 8);
    if ((lane & 15) == 0) beta[(size_t)wid * 4 + h] = p;
}

// K2: xq = x_q @ w_q via 2-product split-bf16 MFMA (A split hi/lo, B bf16-RTN),
// fused gamma epilogue. 256 threads = 4 waves, one per 64-col head group.
// BM=64, BN=256, BK=32. Per wave: 64x64 out = acc[4][4] f32x4 (64 AGPR).
// LDS: Ahi/Alo[64][32] + Bhi[256][32] u16, 16B-chunk swizzle c^(r&3)^((r>>2)&3).
__global__ __launch_bounds__(256, 3) void gemm_gamma_kernel(const float* __restrict__ A,
                                                            const u16* __restrict__ BThi,
                                                            const float* __restrict__ weight,
                                                            u16* __restrict__ xq_out,
                                                            float* __restrict__ gamma, int NQ) {
    __shared__ u16 Ahi_s[64 * 32];
    __shared__ u16 Alo_s[64 * 32];
    __shared__ u16 Bhi_s[256 * 32];

    const int t = threadIdx.x;
    const int lane = t & 63;
    const int wc = t >> 6;         // wave = head / 64-col group
    const int lr = lane & 15;
    const int kg = lane >> 4;
    const long brow = (long)blockIdx.x * 64;

    f32x4 acc[4][4];
#pragma unroll
    for (int m = 0; m < 4; ++m)
#pragma unroll
        for (int n = 0; n < 4; ++n) acc[m][n] = (f32x4){0.f, 0.f, 0.f, 0.f};

    for (int k0 = 0; k0 < DIM; k0 += 32) {
        // stage A tile (64 rows x 32 k) fp32 -> bf16 hi/lo
#pragma unroll
        for (int i = 0; i < 2; ++i) {
            int slot = t + i * 256;
            int row = slot >> 3, c4 = slot & 7;   // c4: 8B unit (4 u16)
            long grow = brow + row;
            if (grow >= NQ) grow = NQ - 1;
            float4 v = *reinterpret_cast<const float4*>(A + grow * DIM + k0 + c4 * 4);
            unsigned h01, l01, h23, l23;
            split2(v.x, v.y, h01, l01);
            split2(v.z, v.w, h23, l23);
            int swz = (c4 >> 1) ^ (row & 3) ^ ((row >> 2) & 3);
            int off = row * 32 + (swz << 3) + ((c4 & 1) << 2);
            *reinterpret_cast<uint2*>(&Ahi_s[off]) = make_uint2(h01, h23);
            *reinterpret_cast<uint2*>(&Alo_s[off]) = make_uint2(l01, l23);
        }
        // stage B tile (256 n x 32 k) from pre-transposed bf16 (L2-resident)
#pragma unroll
        for (int i = 0; i < 4; ++i) {
            int slot = t + i * 256;
            int n = slot >> 2, c = slot & 3;      // c: 16B chunk
            uint4 vh = *reinterpret_cast<const uint4*>(BThi + n * 256 + k0 + c * 8);
            int swz = c ^ (n & 3) ^ ((n >> 2) & 3);
            *reinterpret_cast<uint4*>(&Bhi_s[n * 32 + (swz << 3)]) = vh;
        }
        __syncthreads();

        short8 bh[4];
#pragma unroll
        for (int n = 0; n < 4; ++n) {
            int nn = wc * 64 + n * 16 + lr;
            int off = nn * 32 + ((kg ^ (nn & 3) ^ ((nn >> 2) & 3)) << 3);
            bh[n] = *reinterpret_cast<const short8*>(&Bhi_s[off]);
        }
#pragma unroll
        for (int m = 0; m < 4; ++m) {
            int rr = m * 16 + lr;
            int off = rr * 32 + ((kg ^ (rr & 3) ^ ((rr >> 2) & 3)) << 3);
            short8 ah = *reinterpret_cast<const short8*>(&Ahi_s[off]);
            short8 al = *reinterpret_cast<const short8*>(&Alo_s[off]);
#pragma unroll
            for (int n = 0; n < 4; ++n) {
                acc[m][n] = __builtin_amdgcn_mfma_f32_16x16x32_bf16(ah, bh[n], acc[m][n], 0, 0, 0);
                acc[m][n] = __builtin_amdgcn_mfma_f32_16x16x32_bf16(al, bh[n], acc[m][n], 0, 0, 0);
            }
        }
        __syncthreads();
    }

    // epilogue: bf16 xq stores + fused per-head gamma
    float wv[4];
#pragma unroll
    for (int n = 0; n < 4; ++n) wv[n] = weight[wc * 128 + 64 + n * 16 + lr];

#pragma unroll
    for (int m = 0; m < 4; ++m) {
#pragma unroll
        for (int r = 0; r < 4; ++r) {
            long row = brow + m * 16 + kg * 4 + r;
            bool ok = row < NQ;
            float p = 0.f;
#pragma unroll
            for (int n = 0; n < 4; ++n) {
                float v = acc[m][n][r];
                if (ok) xq_out[row * DIM + wc * 64 + n * 16 + lr] = f2bf(v);
                p = fmaf(v, wv[n], p);
            }
            p += __shfl_xor(p, 1);
            p += __shfl_xor(p, 2);
            p += __shfl_xor(p, 4);
            p += __shfl_xor(p, 8);
            if (ok && lr == 0) gamma[row * 4 + wc] = p;
        }
    }
}

// K3: ex = exp(leaky_relu(beta[eid] + gamma)) — no max-shift needed (|logit| ≲ 7);
// atomicAdd segsum; histogram counts. One pass.
__global__ __launch_bounds__(256) void logits_ex_kernel(const float* __restrict__ beta,
                                                        const float* __restrict__ gamma,
                                                        const int* __restrict__ eids,
                                                        float* __restrict__ exv,
                                                        float* __restrict__ segsum,
                                                        unsigned* __restrict__ counts, int NQ) {
    int e = blockIdx.x * blockDim.x + threadIdx.x;
    if (e >= NQ) return;
    int j = eids[e];
    float4 g = *reinterpret_cast<const float4*>(gamma + (size_t)e * 4);
    float4 b = *reinterpret_cast<const float4*>(beta + (size_t)j * 4);
    float l[4] = {b.x + g.x, b.y + g.y, b.z + g.z, b.w + g.w};
    float ex[4];
#pragma unroll
    for (int h = 0; h < 4; ++h) {
        l[h] = l[h] > 0.f ? l[h] : NEG_SLOPE * l[h];
        ex[h] = __expf(l[h]);
    }
    *reinterpret_cast<float4*>(exv + (size_t)e * 4) = make_float4(ex[0], ex[1], ex[2], ex[3]);
#pragma unroll
    for (int h = 0; h < 4; ++h) atomicAdd(&segsum[(size_t)j * 4 + h], ex[h]);
    atomicAdd(&counts[j], 1u);
}

// ---- CSR build ----
__global__ __launch_bounds__(256) void scan1_kernel(const unsigned* __restrict__ counts,
                                                    unsigned* __restrict__ offs,
                                                    unsigned* __restrict__ blocksums, int NE) {
    __shared__ unsigned s[256];
    int t = threadIdx.x;
    int base = blockIdx.x * 1024 + t * 4;
    unsigned v[4], sum = 0;
#pragma unroll
    for (int i = 0; i < 4; ++i) {
        v[i] = (base + i < NE) ? counts[base + i] : 0u;
        sum += v[i];
    }
    s[t] = sum;
    __syncthreads();
    for (int off = 1; off < 256; off <<= 1) {
        unsigned y = (t >= off) ? s[t - off] : 0u;
        __syncthreads();
        s[t] += y;
        __syncthreads();
    }
    unsigned excl = s[t] - sum;
#pragma unroll
    for (int i = 0; i < 4; ++i) {
        if (base + i < NE) offs[base + i] = excl;
        excl += v[i];
    }
    if (t == 255) blocksums[blockIdx.x] = s[255];
}

__global__ __launch_bounds__(256) void scan2_kernel(unsigned* __restrict__ blocksums, int NB) {
    __shared__ unsigned s[256];
    int t = threadIdx.x;
    unsigned v = (t < NB) ? blocksums[t] : 0u;
    s[t] = v;
    __syncthreads();
    for (int off = 1; off < 256; off <<= 1) {
        unsigned y = (t >= off) ? s[t - off] : 0u;
        __syncthreads();
        s[t] += y;
        __syncthreads();
    }
    if (t < NB) blocksums[t] = s[t] - v;
}

__global__ __launch_bounds__(256) void scan3_kernel(unsigned* __restrict__ offs,
                                                    const unsigned* __restrict__ blocksums,
                                                    unsigned* __restrict__ cursor, int NE) {
    int t = threadIdx.x;
    int base = blockIdx.x * 1024 + t * 4;
    unsigned add = blocksums[blockIdx.x];
#pragma unroll
    for (int i = 0; i < 4; ++i) {
        if (base + i < NE) {
            unsigned o = offs[base + i] + add;
            offs[base + i] = o;
            cursor[base + i] = o;
        }
    }
}

__global__ __launch_bounds__(256) void fill_kernel(const int* __restrict__ eids,
                                                   unsigned* __restrict__ cursor,
                                                   int* __restrict__ qlist, int NQ) {
    int e = blockIdx.x * blockDim.x + threadIdx.x;
    if (e >= NQ) return;
    int j = eids[e];
    unsigned pos = atomicAdd(&cursor[j], 1u);
    qlist[pos] = e;
}

// gather: out[j,:] = sum_{q in seg(j)} (ex[q,h]/(segsum[j,h]+eps)) * xq_bf16[q,:]
__global__ __launch_bounds__(256) void gather_kernel(const float* __restrict__ exv,
                                                     const float* __restrict__ segsum,
                                                     const unsigned* __restrict__ offs,
                                                     const unsigned* __restrict__ counts,
                                                     const int* __restrict__ qlist,
                                                     const u16* __restrict__ xq,
                                                     float* __restrict__ out, int NE) {
    int j = blockIdx.x * 4 + (threadIdx.x >> 6);
    if (j >= NE) return;
    int lane = threadIdx.x & 63;
    int h = lane >> 4;
    unsigned beg = offs[j];
    unsigned n = counts[j];
    float inv = 1.0f / (segsum[(size_t)j * 4 + h] + 1e-16f);
    float4 a0 = make_float4(0.f, 0.f, 0.f, 0.f);
    float4 a1 = make_float4(0.f, 0.f, 0.f, 0.f);
    unsigned i = 0;
    for (; i + 2 <= n; i += 2) {
        int q0 = qlist[beg + i];
        int q1 = qlist[beg + i + 1];
        float w0 = exv[(size_t)q0 * 4 + h] * inv;
        float w1 = exv[(size_t)q1 * 4 + h] * inv;
        u16x4 v0 = *reinterpret_cast<const u16x4*>(xq + (size_t)q0 * DIM + lane * 4);
        u16x4 v1 = *reinterpret_cast<const u16x4*>(xq + (size_t)q1 * DIM + lane * 4);
        a0.x = fmaf(w0, bf2f(v0.x), a0.x); a1.x = fmaf(w1, bf2f(v1.x), a1.x);
        a0.y = fmaf(w0, bf2f(v0.y), a0.y); a1.y = fmaf(w1, bf2f(v1.y), a1.y);
        a0.z = fmaf(w0, bf2f(v0.z), a0.z); a1.z = fmaf(w1, bf2f(v1.z), a1.z);
        a0.w = fmaf(w0, bf2f(v0.w), a0.w); a1.w = fmaf(w1, bf2f(v1.w), a1.w);
    }
    if (i < n) {
        int q0 = qlist[beg + i];
        float w0 = exv[(size_t)q0 * 4 + h] * inv;
        u16x4 v0 = *reinterpret_cast<const u16x4*>(xq + (size_t)q0 * DIM + lane * 4);
        a0.x = fmaf(w0, bf2f(v0.x), a0.x);
        a0.y = fmaf(w0, bf2f(v0.y), a0.y);
        a0.z = fmaf(w0, bf2f(v0.z), a0.z);
        a0.w = fmaf(w0, bf2f(v0.w), a0.w);
    }
    float4 acc = make_float4(a0.x + a1.x, a0.y + a1.y, a0.z + a1.z, a0.w + a1.w);
    *reinterpret_cast<float4*>(out + (size_t)j * DIM + lane * 4) = acc;
}

extern "C" void kernel_launch(void* const* d_in, const int* in_sizes, int n_in,
                              void* d_out, int out_size, void* d_ws, size_t ws_size,
                              hipStream_t stream) {
    (void)n_in; (void)out_size; (void)ws_size;
    const float* x_q    = (const float*)d_in[0];
    const float* x_edge = (const float*)d_in[1];
    const float* w_q    = (const float*)d_in[2];
    const float* weight = (const float*)d_in[3];
    const int*   eids   = (const int*)d_in[4];
    const int NQ = in_sizes[0] / DIM;   // 500000
    const int NE = in_sizes[1] / DIM;   // 250000
    float* out = (float*)d_out;

    // workspace layout
    u16*      xq        = (u16*)d_ws;                           // NQ*256 bf16
    float*    gamma     = (float*)(xq + (size_t)NQ * DIM);      // NQ*4
    float*    exv       = gamma + (size_t)NQ * 4;               // NQ*4
    float*    beta      = exv + (size_t)NQ * 4;                 // NE*4
    float*    segsum    = beta + (size_t)NE * 4;                // NE*4
    unsigned* counts    = (unsigned*)(segsum + (size_t)NE * 4); // NE
    unsigned* offs      = counts + NE;                          // NE
    unsigned* cursor    = offs + NE;                            // NE
    int*      qlist     = (int*)(cursor + NE);                  // NQ
    unsigned* blocksums = (unsigned*)(qlist + NQ);              // 256
    u16*      BThi      = (u16*)(blocksums + 256);              // 256*256

    const int NB = (NE + 1023) / 1024;

    hipMemsetAsync(segsum, 0, (size_t)NE * 4 * sizeof(float), stream);
    hipMemsetAsync(counts, 0, (size_t)NE * sizeof(unsigned), stream);

    prepb_kernel<<<256, 256, 0, stream>>>(w_q, BThi);
    beta_kernel<<<(NE + 3) / 4, 256, 0, stream>>>(x_edge, weight, beta, NE);
    gemm_gamma_kernel<<<(NQ + 63) / 64, 256, 0, stream>>>(x_q, BThi, weight, xq, gamma, NQ);
    logits_ex_kernel<<<(NQ + 255) / 256, 256, 0, stream>>>(beta, gamma, eids, exv, segsum, counts, NQ);
    scan1_kernel<<<NB, 256, 0, stream>>>(counts, offs, blocksums, NE);
    scan2_kernel<<<1, 256, 0, stream>>>(blocksums, NB);
    scan3_kernel<<<NB, 256, 0, stream>>>(offs, blocksums, cursor, NE);
    fill_kernel<<<(NQ + 255) / 256, 256, 0, stream>>>(eids, cursor, qlist, NQ);
    gather_kernel<<<(NE + 3) / 4, 256, 0, stream>>>(exv, segsum, offs, counts, qlist, xq, out, NE);
}

// Round 7
// 562.738 us; speedup vs baseline: 4.0866x; 1.0337x over previous
//
#include <hip/hip_runtime.h>
#include <hip/hip_bf16.h>

#define DIM 256
#define HEADS 4
#define NEG_SLOPE 0.01f

typedef unsigned short u16;
typedef __attribute__((ext_vector_type(8))) short short8;
typedef __attribute__((ext_vector_type(4))) float f32x4;
typedef __attribute__((ext_vector_type(4))) unsigned short u16x4;

// ---- bf16 helpers ----
__device__ __forceinline__ u16 f2bf(float f) {           // RTN-even
    unsigned u = __float_as_uint(f);
    unsigned r = (u + 0x7fffu + ((u >> 16) & 1u)) >> 16;
    return (u16)r;
}
__device__ __forceinline__ float bf2f(u16 h) {
    return __uint_as_float(((unsigned)h) << 16);
}

// K0: transpose w_q (k-major fp32) -> BThi (n-major bf16, RTN)
__global__ __launch_bounds__(256) void prepb_kernel(const float* __restrict__ B,
                                                    u16* __restrict__ BThi) {
    int k = blockIdx.x;
    int n = threadIdx.x;
    BThi[n * 256 + k] = f2bf(B[k * 256 + n]);
}

// K1: beta[j,h] = sum_{d<64} x_edge[j, h*64+d] * weight[h, d]
__global__ __launch_bounds__(256) void beta_kernel(const float* __restrict__ xe,
                                                   const float* __restrict__ weight,
                                                   float* __restrict__ beta, int NE) {
    int wid = blockIdx.x * 4 + (threadIdx.x >> 6);
    if (wid >= NE) return;
    int lane = threadIdx.x & 63;
    int h = lane >> 4;
    float4 v = *reinterpret_cast<const float4*>(xe + (size_t)wid * DIM + lane * 4);
    float4 w = *reinterpret_cast<const float4*>(weight + h * 128 + (lane & 15) * 4);
    float p = v.x * w.x + v.y * w.y + v.z * w.z + v.w * w.w;
    p += __shfl_xor(p, 1);
    p += __shfl_xor(p, 2);
    p += __shfl_xor(p, 4);
    p += __shfl_xor(p, 8);
    if ((lane & 15) == 0) beta[(size_t)wid * 4 + h] = p;
}

// K2: xq = x_q @ w_q via bf16 MFMA (A RTN-bf16, B RTN-bf16), fused epilogue:
//   gamma (per-head dot) -> logit = leaky(beta[eid]+gamma) -> ex = exp(logit)
//   -> exv store, segsum atomicAdd, counts histogram. No gamma round-trip.
// 256 threads = 4 waves, one per 64-col head group. BM=64, BN=256, BK=32.
// Per wave: 64x64 out = acc[4][4] f32x4 (64 AGPR).
// LDS: Ahi[64][32] + Bhi[256][32] u16, 16B-chunk swizzle c^(r&3)^((r>>2)&3).
__global__ __launch_bounds__(256, 3) void gemm_fused_kernel(const float* __restrict__ A,
                                                            const u16* __restrict__ BThi,
                                                            const float* __restrict__ weight,
                                                            const float* __restrict__ beta,
                                                            const int* __restrict__ eids,
                                                            u16* __restrict__ xq_out,
                                                            float* __restrict__ exv,
                                                            float* __restrict__ segsum,
                                                            unsigned* __restrict__ counts,
                                                            int NQ) {
    __shared__ u16 Ahi_s[64 * 32];
    __shared__ u16 Bhi_s[256 * 32];

    const int t = threadIdx.x;
    const int lane = t & 63;
    const int wc = t >> 6;         // wave = head / 64-col group
    const int lr = lane & 15;
    const int kg = lane >> 4;
    const long brow = (long)blockIdx.x * 64;

    f32x4 acc[4][4];
#pragma unroll
    for (int m = 0; m < 4; ++m)
#pragma unroll
        for (int n = 0; n < 4; ++n) acc[m][n] = (f32x4){0.f, 0.f, 0.f, 0.f};

    for (int k0 = 0; k0 < DIM; k0 += 32) {
        // stage A tile (64 rows x 32 k) fp32 -> bf16 (RTN)
#pragma unroll
        for (int i = 0; i < 2; ++i) {
            int slot = t + i * 256;
            int row = slot >> 3, c4 = slot & 7;   // c4: 8B unit (4 u16)
            long grow = brow + row;
            if (grow >= NQ) grow = NQ - 1;
            float4 v = *reinterpret_cast<const float4*>(A + grow * DIM + k0 + c4 * 4);
            u16x4 hv;
            hv.x = f2bf(v.x); hv.y = f2bf(v.y); hv.z = f2bf(v.z); hv.w = f2bf(v.w);
            int swz = (c4 >> 1) ^ (row & 3) ^ ((row >> 2) & 3);
            int off = row * 32 + (swz << 3) + ((c4 & 1) << 2);
            *reinterpret_cast<u16x4*>(&Ahi_s[off]) = hv;
        }
        // stage B tile (256 n x 32 k) from pre-transposed bf16 (L2-resident)
#pragma unroll
        for (int i = 0; i < 4; ++i) {
            int slot = t + i * 256;
            int n = slot >> 2, c = slot & 3;      // c: 16B chunk
            uint4 vh = *reinterpret_cast<const uint4*>(BThi + n * 256 + k0 + c * 8);
            int swz = c ^ (n & 3) ^ ((n >> 2) & 3);
            *reinterpret_cast<uint4*>(&Bhi_s[n * 32 + (swz << 3)]) = vh;
        }
        __syncthreads();

        short8 bh[4];
#pragma unroll
        for (int n = 0; n < 4; ++n) {
            int nn = wc * 64 + n * 16 + lr;
            int off = nn * 32 + ((kg ^ (nn & 3) ^ ((nn >> 2) & 3)) << 3);
            bh[n] = *reinterpret_cast<const short8*>(&Bhi_s[off]);
        }
#pragma unroll
        for (int m = 0; m < 4; ++m) {
            int rr = m * 16 + lr;
            int off = rr * 32 + ((kg ^ (rr & 3) ^ ((rr >> 2) & 3)) << 3);
            short8 ah = *reinterpret_cast<const short8*>(&Ahi_s[off]);
#pragma unroll
            for (int n = 0; n < 4; ++n)
                acc[m][n] = __builtin_amdgcn_mfma_f32_16x16x32_bf16(ah, bh[n], acc[m][n], 0, 0, 0);
        }
        __syncthreads();
    }

    // epilogue: bf16 xq stores + per-head gamma -> ex -> segsum/counts
    float wv[4];
#pragma unroll
    for (int n = 0; n < 4; ++n) wv[n] = weight[wc * 128 + 64 + n * 16 + lr];

#pragma unroll
    for (int m = 0; m < 4; ++m) {
#pragma unroll
        for (int r = 0; r < 4; ++r) {
            long row = brow + m * 16 + kg * 4 + r;
            bool ok = row < NQ;
            float p = 0.f;
#pragma unroll
            for (int n = 0; n < 4; ++n) {
                float v = acc[m][n][r];
                if (ok) xq_out[row * DIM + wc * 64 + n * 16 + lr] = f2bf(v);
                p = fmaf(v, wv[n], p);
            }
            p += __shfl_xor(p, 1);
            p += __shfl_xor(p, 2);
            p += __shfl_xor(p, 4);
            p += __shfl_xor(p, 8);
            if (ok && lr == 0) {
                int j = eids[row];
                float l = beta[(size_t)j * 4 + wc] + p;
                l = l > 0.f ? l : NEG_SLOPE * l;
                float e = __expf(l);
                exv[row * 4 + wc] = e;
                atomicAdd(&segsum[(size_t)j * 4 + wc], e);
                if (wc == 0) atomicAdd(&counts[j], 1u);
            }
        }
    }
}

// ---- CSR build ----
__global__ __launch_bounds__(256) void scan1_kernel(const unsigned* __restrict__ counts,
                                                    unsigned* __restrict__ offs,
                                                    unsigned* __restrict__ blocksums, int NE) {
    __shared__ unsigned s[256];
    int t = threadIdx.x;
    int base = blockIdx.x * 1024 + t * 4;
    unsigned v[4], sum = 0;
#pragma unroll
    for (int i = 0; i < 4; ++i) {
        v[i] = (base + i < NE) ? counts[base + i] : 0u;
        sum += v[i];
    }
    s[t] = sum;
    __syncthreads();
    for (int off = 1; off < 256; off <<= 1) {
        unsigned y = (t >= off) ? s[t - off] : 0u;
        __syncthreads();
        s[t] += y;
        __syncthreads();
    }
    unsigned excl = s[t] - sum;
#pragma unroll
    for (int i = 0; i < 4; ++i) {
        if (base + i < NE) offs[base + i] = excl;
        excl += v[i];
    }
    if (t == 255) blocksums[blockIdx.x] = s[255];
}

__global__ __launch_bounds__(256) void scan2_kernel(unsigned* __restrict__ blocksums, int NB) {
    __shared__ unsigned s[256];
    int t = threadIdx.x;
    unsigned v = (t < NB) ? blocksums[t] : 0u;
    s[t] = v;
    __syncthreads();
    for (int off = 1; off < 256; off <<= 1) {
        unsigned y = (t >= off) ? s[t - off] : 0u;
        __syncthreads();
        s[t] += y;
        __syncthreads();
    }
    if (t < NB) blocksums[t] = s[t] - v;
}

__global__ __launch_bounds__(256) void scan3_kernel(unsigned* __restrict__ offs,
                                                    const unsigned* __restrict__ blocksums,
                                                    unsigned* __restrict__ cursor, int NE) {
    int t = threadIdx.x;
    int base = blockIdx.x * 1024 + t * 4;
    unsigned add = blocksums[blockIdx.x];
#pragma unroll
    for (int i = 0; i < 4; ++i) {
        if (base + i < NE) {
            unsigned o = offs[base + i] + add;
            offs[base + i] = o;
            cursor[base + i] = o;
        }
    }
}

__global__ __launch_bounds__(256) void fill_kernel(const int* __restrict__ eids,
                                                   unsigned* __restrict__ cursor,
                                                   int* __restrict__ qlist, int NQ) {
    int e = blockIdx.x * blockDim.x + threadIdx.x;
    if (e >= NQ) return;
    int j = eids[e];
    unsigned pos = atomicAdd(&cursor[j], 1u);
    qlist[pos] = e;
}

// gather: out[j,:] = sum_{q in seg(j)} (ex[q,h]/(segsum[j,h]+eps)) * xq_bf16[q,:]
__global__ __launch_bounds__(256) void gather_kernel(const float* __restrict__ exv,
                                                     const float* __restrict__ segsum,
                                                     const unsigned* __restrict__ offs,
                                                     const unsigned* __restrict__ counts,
                                                     const int* __restrict__ qlist,
                                                     const u16* __restrict__ xq,
                                                     float* __restrict__ out, int NE) {
    int j = blockIdx.x * 4 + (threadIdx.x >> 6);
    if (j >= NE) return;
    int lane = threadIdx.x & 63;
    int h = lane >> 4;
    unsigned beg = offs[j];
    unsigned n = counts[j];
    float inv = 1.0f / (segsum[(size_t)j * 4 + h] + 1e-16f);
    float4 a0 = make_float4(0.f, 0.f, 0.f, 0.f);
    float4 a1 = make_float4(0.f, 0.f, 0.f, 0.f);
    unsigned i = 0;
    for (; i + 2 <= n; i += 2) {
        int q0 = qlist[beg + i];
        int q1 = qlist[beg + i + 1];
        float w0 = exv[(size_t)q0 * 4 + h] * inv;
        float w1 = exv[(size_t)q1 * 4 + h] * inv;
        u16x4 v0 = *reinterpret_cast<const u16x4*>(xq + (size_t)q0 * DIM + lane * 4);
        u16x4 v1 = *reinterpret_cast<const u16x4*>(xq + (size_t)q1 * DIM + lane * 4);
        a0.x = fmaf(w0, bf2f(v0.x), a0.x); a1.x = fmaf(w1, bf2f(v1.x), a1.x);
        a0.y = fmaf(w0, bf2f(v0.y), a0.y); a1.y = fmaf(w1, bf2f(v1.y), a1.y);
        a0.z = fmaf(w0, bf2f(v0.z), a0.z); a1.z = fmaf(w1, bf2f(v1.z), a1.z);
        a0.w = fmaf(w0, bf2f(v0.w), a0.w); a1.w = fmaf(w1, bf2f(v1.w), a1.w);
    }
    if (i < n) {
        int q0 = qlist[beg + i];
        float w0 = exv[(size_t)q0 * 4 + h] * inv;
        u16x4 v0 = *reinterpret_cast<const u16x4*>(xq + (size_t)q0 * DIM + lane * 4);
        a0.x = fmaf(w0, bf2f(v0.x), a0.x);
        a0.y = fmaf(w0, bf2f(v0.y), a0.y);
        a0.z = fmaf(w0, bf2f(v0.z), a0.z);
        a0.w = fmaf(w0, bf2f(v0.w), a0.w);
    }
    float4 acc = make_float4(a0.x + a1.x, a0.y + a1.y, a0.z + a1.z, a0.w + a1.w);
    *reinterpret_cast<float4*>(out + (size_t)j * DIM + lane * 4) = acc;
}

extern "C" void kernel_launch(void* const* d_in, const int* in_sizes, int n_in,
                              void* d_out, int out_size, void* d_ws, size_t ws_size,
                              hipStream_t stream) {
    (void)n_in; (void)out_size; (void)ws_size;
    const float* x_q    = (const float*)d_in[0];
    const float* x_edge = (const float*)d_in[1];
    const float* w_q    = (const float*)d_in[2];
    const float* weight = (const float*)d_in[3];
    const int*   eids   = (const int*)d_in[4];
    const int NQ = in_sizes[0] / DIM;   // 500000
    const int NE = in_sizes[1] / DIM;   // 250000
    float* out = (float*)d_out;

    // workspace layout
    u16*      xq        = (u16*)d_ws;                           // NQ*256 bf16
    float*    exv       = (float*)(xq + (size_t)NQ * DIM);      // NQ*4
    float*    beta      = exv + (size_t)NQ * 4;                 // NE*4
    float*    segsum    = beta + (size_t)NE * 4;                // NE*4
    unsigned* counts    = (unsigned*)(segsum + (size_t)NE * 4); // NE
    unsigned* offs      = counts + NE;                          // NE
    unsigned* cursor    = offs + NE;                            // NE
    int*      qlist     = (int*)(cursor + NE);                  // NQ
    unsigned* blocksums = (unsigned*)(qlist + NQ);              // 256
    u16*      BThi      = (u16*)(blocksums + 256);              // 256*256

    const int NB = (NE + 1023) / 1024;

    hipMemsetAsync(segsum, 0, (size_t)NE * 4 * sizeof(float), stream);
    hipMemsetAsync(counts, 0, (size_t)NE * sizeof(unsigned), stream);

    prepb_kernel<<<256, 256, 0, stream>>>(w_q, BThi);
    beta_kernel<<<(NE + 3) / 4, 256, 0, stream>>>(x_edge, weight, beta, NE);
    gemm_fused_kernel<<<(NQ + 63) / 64, 256, 0, stream>>>(x_q, BThi, weight, beta, eids,
                                                          xq, exv, segsum, counts, NQ);
    scan1_kernel<<<NB, 256, 0, stream>>>(counts, offs, blocksums, NE);
    scan2_kernel<<<1, 256, 0, stream>>>(blocksums, NB);
    scan3_kernel<<<NB, 256, 0, stream>>>(offs, blocksums, cursor, NE);
    fill_kernel<<<(NQ + 255) / 256, 256, 0, stream>>>(eids, cursor, qlist, NQ);
    gather_kernel<<<(NE + 3) / 4, 256, 0, stream>>>(exv, segsum, offs, counts, qlist, xq, out, NE);
}